// Round 6
// baseline (1270.468 us; speedup 1.0000x reference)
//
#include <hip/hip_runtime.h>
#include <math.h>

// Fused Conv3d(3->16, k=3, valid) + bias + min over D + softmax over C.
// N=16, CIN=3, COUT=16, K=3, D=H=W=64 -> out [16,16,62,62] fp32.
//
// R9: R8 geometry (4 px/thread, tile 4h x 16w, grid 1024, double-buffered
// global_load_lds staging) + __launch_bounds__(256, 2).
// Occupancy ladder so far: R4 VGPR=228 -> 2 waves/SIMD, 245us.
// R8 VGPR=168 -> STILL 2 waves/SIMD (gfx950 occupancy steps at VGPR=
// 64/128/256 per m69; no 3-wave bin) -> neutral 261us, Occupancy 11.5%
// identical to R4. R7's (256,4) empirically set cap=64 (=256/4), i.e.
// the arg acts at 2x documented strength; so (256,2) should set cap=128
// = the 4-waves/SIMD bin. Arch need ~120 regs (81 wreg + 12 ring + 4 mv
// + 3 goff + transients) -> 128 should fit by squeezing scheduler slack.
// Outcomes: cap=128 clean -> ~1.5x (TLP doubles, stall fraction halves);
// cap=256 (mapping wrong) -> neutral; cap=128 w/ spill -> WRITE_SIZE
// balloons (tripwire, revert next round).
// Tripwires: VGPR==128?, WRITE_SIZE ~5.3MB = clean.

#define CH 8  // d-slices per staged chunk

// apply taps (kh) for current (ci): 3 kw x 4 p x 3 kd FMAs on one row
#define TAPS(kh)                                                           \
    _Pragma("unroll")                                                      \
    for (int kw = 0; kw < 3; ++kw) {                                       \
        const float wk0 = wreg[ci * 27 + 0  + (kh) * 3 + kw];              \
        const float wk1 = wreg[ci * 27 + 9  + (kh) * 3 + kw];              \
        const float wk2 = wreg[ci * 27 + 18 + (kh) * 3 + kw];              \
        _Pragma("unroll")                                                  \
        for (int p = 0; p < 4; ++p) {                                      \
            const float xv = row[kw + p];                                  \
            A2[p] = fmaf(xv, wk0, A2[p]); /* d' = d   */                   \
            A1[p] = fmaf(xv, wk1, A1[p]); /* d' = d-1 */                   \
            A0[p] = fmaf(xv, wk2, A0[p]); /* d' = d-2 */                   \
        }                                                                  \
    }

__global__ __launch_bounds__(256, 2) void conv3d_min_softmax(
    const float* __restrict__ x,     // [16,3,64,64,64]
    const float* __restrict__ wgt,   // [16,3,3,3,3]
    const float* __restrict__ bias,  // [16]
    float* __restrict__ out)         // [16,16,62,62]
{
    const int tid = threadIdx.x;
    const int co  = tid & 15;          // output channel on lane bits 0..3
    const int s   = tid >> 4;          // 0..15 strip id
    const int R   = s >> 2;            // output row within tile (0..3)
    const int wc  = (s & 3) * 4;       // output cols wc..wc+3 (0,4,8,12)
    const int n   = blockIdx.z;
    const int h0  = blockIdx.y * 4;    // 16 h-tiles cover rows 0..63 (62 valid)
    const int w0  = blockIdx.x * 16;   // 4 w-tiles cover cols 0..63 (62 valid)

    // staged x, double-buffered. Logical layout per buffer:
    // [3 ci][CH dd][6 rows][20 cols] = 2880 floats (11520 B), padded to
    // 768 float4 (12288 B) so every thread issues exactly 3 DMAs.
    __shared__ __align__(16) float sx[2][768 * 4];

    // per-thread weights: idx = ci*27 + kd*9 + kh*3 + kw
    float wreg[81];
#pragma unroll
    for (int i = 0; i < 81; ++i) wreg[i] = wgt[co * 81 + i];

    // ---- hoisted staging address math (chunk 0, d0 = 0) ----
    // float4 slot F = tid + 256*k maps to LDS byte offset F*16 (lane-linear)
    // and global float index (((ci*64 + dd)*64 + gh)*64 + gw).
    int goff[3];  // global BYTE offsets for k = 0..2
#pragma unroll
    for (int k = 0; k < 3; ++k) {
        int F  = tid + 256 * k;
        int Fc = F < 720 ? F : 719;      // pad region: harmless dup fetch
        int rowid = Fc / 5;              // ci*(CH*6) + dd*6 + r
        int g     = Fc - rowid * 5;      // col group (4 floats)
        int ci    = rowid / (CH * 6);
        int rem   = rowid - ci * (CH * 6);
        int dd    = rem / 6;
        int r     = rem - dd * 6;
        int gh    = min(h0 + r, 63);     // clamp: edge halo, unused
        int gw    = min(w0 + g * 4, 60); // clamp: cols >=62 unused
        goff[k]   = (((ci * 64 + dd) * 64 + gh) * 64 + gw) * 4;
    }
    const char* xb = (const char*)(x + (size_t)n * 3 * 64 * 64 * 64);

    // ring: A0 completes this step (kd=2), A1 next (kd=1), A2 after (kd=0)
    float A0[4], A1[4], A2[4], mv[4];
#pragma unroll
    for (int p = 0; p < 4; ++p) {
        A0[p] = A1[p] = A2[p] = 0.f;
        mv[p] = 1e30f;
    }

    // ---- issue chunk 0 DMA (into buffer 0) ----
    {
        char* lds0 = (char*)&sx[0][0] + tid * 16;
#pragma unroll
        for (int k = 0; k < 3; ++k)
            __builtin_amdgcn_global_load_lds(
                (const void*)(xb + goff[k]), (void*)(lds0 + k * 4096),
                16, 0, 0);
    }

    for (int c = 0; c < 64 / CH; ++c) {
        // Drains vmcnt(0): chunk c's DMA has landed; all waves are done
        // reading the other buffer, so it is free to be overwritten below.
        __syncthreads();

        // ---- issue chunk c+1 DMA; flies during this chunk's compute ----
        if (c < 7) {
            const char* xc = xb + (size_t)(c + 1) * (CH * 64 * 64 * 4);
            char* ldsn = (char*)&sx[(c + 1) & 1][0] + tid * 16;
#pragma unroll
            for (int k = 0; k < 3; ++k)
                __builtin_amdgcn_global_load_lds(
                    (const void*)(xc + goff[k]), (void*)(ldsn + k * 4096),
                    16, 0, 0);
        }

        // compute reads the buffer whose DMA completed at the barrier
        const float* S = sx[c & 1];
        const int d0 = c * CH;

        // ---- compute CH d-steps from LDS ----
#pragma unroll 1
        for (int dd = 0; dd < CH; ++dd) {
#pragma unroll
            for (int ci = 0; ci < 3; ++ci) {
#pragma unroll
                for (int kh = 0; kh < 3; ++kh) {
                    const int base =
                        (ci * (CH * 6) + dd * 6 + R + kh) * 20 + wc;
                    const float4 a = *(const float4*)&S[base];
                    const float2 b = *(const float2*)&S[base + 4];
                    const float row[6] = {a.x, a.y, a.z, a.w, b.x, b.y};
                    TAPS(kh)
                }
            }
            const int d = d0 + dd;
            if (d >= 2) {
#pragma unroll
                for (int p = 0; p < 4; ++p)
                    mv[p] = fminf(mv[p], A0[p]);
            }
#pragma unroll
            for (int p = 0; p < 4; ++p) {
                A0[p] = A1[p];
                A1[p] = A2[p];
                A2[p] = 0.f;
            }
        }
    }

    // ---- epilogue: bias, softmax over 16 channels (lanes), store ----
    const float bv = bias[co];
    const int hp = h0 + R;
#pragma unroll
    for (int p = 0; p < 4; ++p) {
        float v = mv[p] + bv;
        float mx = v;
#pragma unroll
        for (int off = 1; off < 16; off <<= 1)
            mx = fmaxf(mx, __shfl_xor(mx, off, 64));
        float e = __expf(v - mx);
        float sum = e;
#pragma unroll
        for (int off = 1; off < 16; off <<= 1)
            sum += __shfl_xor(sum, off, 64);
        const int wp = w0 + wc + p;
        if (hp < 62 && wp < 62)
            out[(((size_t)n * 16 + co) * 62 + hp) * 62 + wp] = e / sum;
    }
}

extern "C" void kernel_launch(void* const* d_in, const int* in_sizes, int n_in,
                              void* d_out, int out_size, void* d_ws, size_t ws_size,
                              hipStream_t stream) {
    const float* x    = (const float*)d_in[0];
    const float* wgt  = (const float*)d_in[1];
    const float* bias = (const float*)d_in[2];
    float* out        = (float*)d_out;
    dim3 grid(4, 16, 16);  // (w-tiles, h-tiles, n)
    dim3 block(256);
    hipLaunchKernelGGL(conv3d_min_softmax, grid, block, 0, stream,
                       x, wgt, bias, out);
}

// Round 7
// 605.056 us; speedup vs baseline: 2.0998x; 2.0998x over previous
//
#include <hip/hip_runtime.h>
#include <math.h>

// Fused Conv3d(3->16, k=3, valid) + bias + min over D + softmax over C.
// N=16, CIN=3, COUT=16, K=3, D=H=W=64 -> out [16,16,62,62] fp32.
//
// R10: structural rewrite — weights move VGPR -> SGPR.
// History: R4 228 VGPR -> 2 waves/SIMD, 245us. R8 168 VGPR -> same bin,
// neutral. R9 cap=128 -> spilled 158MB scratch. The wreg[81] design has a
// ~168-VGPR architectural floor; no cap can fix it.
// Fix: block = 1024 thr = 16 waves; wave w owns co=w, so weights are
// wave-uniform -> co = readfirstlane(tid>>6) -> 81 scalar loads -> SGPRs
// (~95 of 102). v_fmac_f32 takes the weight as its one SGPR operand.
// Per-thread VGPR state ~40 (ring 6 + mv 2 + transients): with
// amdgpu_waves_per_eu(8) targets the 64-VGPR bin -> 8 waves/SIMD,
// 2048 thr/CU (vs 2 waves/SIMD since R4). Spill risk mild: the hot
// 81-value array is no longer vector state.
// Tile 4h x 32w, 2 px/thread; grid (2,16,16) = 512 blocks = 2/CU.
// Staging: proven double-buffered global_load_lds, 1296 float4 slots.
// Softmax crosses waves via stride-17 LDS exchange (epilogue-only).
// Tripwires: VGPR<=64? SGPR~100? WRITE_SIZE ~5.3MB = clean.

#define CH 8  // d-slices per staged chunk

__global__ __launch_bounds__(1024)
__attribute__((amdgpu_waves_per_eu(8)))
void conv3d_min_softmax(
    const float* __restrict__ x,     // [16,3,64,64,64]
    const float* __restrict__ wgt,   // [16,3,3,3,3]
    const float* __restrict__ bias,  // [16]
    float* __restrict__ out)         // [16,16,62,62]
{
    const int tid = threadIdx.x;
    // wave id == output channel; readfirstlane forces wave-uniform -> SGPR
    const int wv  = __builtin_amdgcn_readfirstlane(tid >> 6);
    const int l   = tid & 63;
    const int r0  = l >> 4;           // output row within tile (0..3)
    const int cg  = l & 15;           // col-pair group (0..15)
    const int wc  = cg * 2;           // tile col of px0 (even -> 8B aligned)
    const int n   = blockIdx.z;
    const int h0  = blockIdx.y * 4;   // 16 h-tiles cover rows 0..63 (62 valid)
    const int w0  = blockIdx.x * 32;  // 2 w-tiles cover cols 0..63 (62 valid)

    // staged x, double-buffered: [3 ci][CH dd][6 rows][36 cols] = 5184 f
    // = 1296 float4 slots (slot F <-> float index 4F, lane-linear for DMA).
    __shared__ __align__(16) float sx[2][5184];
    // softmax exchange: [128 px][17] (stride 17 -> conflict-free reads)
    __shared__ float sm[128 * 17];

    // ---- wave-uniform weights -> SGPRs; idx = ci*27 + kd*9 + kh*3 + kw
    float ws[81];
#pragma unroll
    for (int i = 0; i < 81; ++i) ws[i] = wgt[wv * 81 + i];
    const float bv = bias[wv];

    // ---- hoisted staging address math (chunk 0) ----
    // slot F -> (ci, dd, r, g):  F = ((ci*8+dd)*6 + r)*9 + g
    int goff[2];  // global BYTE offsets; k=1 used only by tid<272
#pragma unroll
    for (int k = 0; k < 2; ++k) {
        int F = tid + 1024 * k;
        if (F > 1295) F = 1295;          // unused lanes: harmless dup
        int ci  = F / 432;               // 432 = 8*6*9
        int rem = F - ci * 432;
        int dd  = rem / 54;              // 54 = 6*9
        int rr  = rem - dd * 54;
        int rw  = rr / 9;
        int g   = rr - rw * 9;
        int gh  = h0 + rw;  if (gh > 63) gh = 63;  // clamp: halo, unused
        int gw  = w0 + g * 4; if (gw > 60) gw = 60; // clamp: cols>=62 unused
        goff[k] = (((ci * 64 + dd) * 64 + gh) * 64 + gw) * 4;
    }
    const char* xb = (const char*)(x + (size_t)n * 3 * 64 * 64 * 64);

    // ring: A0 completes this step (kd=2), A1 next (kd=1), A2 after (kd=0)
    float A0[2], A1[2], A2[2], mv[2];
#pragma unroll
    for (int p = 0; p < 2; ++p) {
        A0[p] = A1[p] = A2[p] = 0.f;
        mv[p] = 1e30f;
    }

    // ---- issue chunk 0 DMA (buffer 0) ----
    {
        char* lb = (char*)&sx[0][0];
        __builtin_amdgcn_global_load_lds(
            (const void*)(xb + goff[0]), (void*)(lb + tid * 16), 16, 0, 0);
        if (tid < 272)
            __builtin_amdgcn_global_load_lds(
                (const void*)(xb + goff[1]),
                (void*)(lb + (1024 + tid) * 16), 16, 0, 0);
    }

    for (int c = 0; c < 64 / CH; ++c) {
        // Drains vmcnt(0): chunk c's DMA landed; other buffer now free.
        __syncthreads();

        // ---- issue chunk c+1 DMA; flies during this chunk's compute ----
        if (c < 7) {
            const char* xc = xb + (size_t)(c + 1) * (CH * 64 * 64 * 4);
            char* lb = (char*)&sx[(c + 1) & 1][0];
            __builtin_amdgcn_global_load_lds(
                (const void*)(xc + goff[0]), (void*)(lb + tid * 16),
                16, 0, 0);
            if (tid < 272)
                __builtin_amdgcn_global_load_lds(
                    (const void*)(xc + goff[1]),
                    (void*)(lb + (1024 + tid) * 16), 16, 0, 0);
        }

        const float* S = sx[c & 1];
        const int d0 = c * CH;

        // ---- compute CH d-steps from LDS ----
#pragma unroll 2
        for (int dd = 0; dd < CH; ++dd) {
#pragma unroll
            for (int ci = 0; ci < 3; ++ci) {
#pragma unroll
                for (int kh = 0; kh < 3; ++kh) {
                    const int base =
                        ((ci * CH + dd) * 6 + r0 + kh) * 36 + wc;
                    const float2 a = *(const float2*)&S[base];      // x0,x1
                    const float2 b = *(const float2*)&S[base + 2];  // x2,x3
                    const float row[4] = {a.x, a.y, b.x, b.y};
#pragma unroll
                    for (int kw = 0; kw < 3; ++kw) {
                        const float wk0 = ws[ci * 27 + 0  + kh * 3 + kw];
                        const float wk1 = ws[ci * 27 + 9  + kh * 3 + kw];
                        const float wk2 = ws[ci * 27 + 18 + kh * 3 + kw];
#pragma unroll
                        for (int p = 0; p < 2; ++p) {
                            const float xv = row[kw + p];
                            A2[p] = fmaf(xv, wk0, A2[p]); /* d' = d   */
                            A1[p] = fmaf(xv, wk1, A1[p]); /* d' = d-1 */
                            A0[p] = fmaf(xv, wk2, A0[p]); /* d' = d-2 */
                        }
                    }
                }
            }
            if (d0 + dd >= 2) {
                mv[0] = fminf(mv[0], A0[0]);
                mv[1] = fminf(mv[1], A0[1]);
            }
            A0[0] = A1[0]; A0[1] = A1[1];
            A1[0] = A2[0]; A1[1] = A2[1];
            A2[0] = 0.f;   A2[1] = 0.f;
        }
    }

    // ---- epilogue: exchange via LDS, softmax over 16 channels ----
    const int px0 = r0 * 32 + wc;
    sm[px0 * 17 + wv]       = mv[0] + bv;
    sm[(px0 + 1) * 17 + wv] = mv[1] + bv;
    __syncthreads();

    const int hp = h0 + r0;
#pragma unroll
    for (int pp = 0; pp < 2; ++pp) {
        const int px = px0 + pp;
        float mx = -1e30f;
#pragma unroll
        for (int j = 0; j < 16; ++j) mx = fmaxf(mx, sm[px * 17 + j]);
        float sum = 0.f;
#pragma unroll
        for (int j = 0; j < 16; ++j) sum += __expf(sm[px * 17 + j] - mx);
        const int wp = w0 + wc + pp;
        if (hp < 62 && wp < 62) {
            const float e = __expf(sm[px * 17 + wv] - mx);
            out[(((size_t)n * 16 + wv) * 62 + hp) * 62 + wp] = e / sum;
        }
    }
}

extern "C" void kernel_launch(void* const* d_in, const int* in_sizes, int n_in,
                              void* d_out, int out_size, void* d_ws, size_t ws_size,
                              hipStream_t stream) {
    const float* x    = (const float*)d_in[0];
    const float* wgt  = (const float*)d_in[1];
    const float* bias = (const float*)d_in[2];
    float* out        = (float*)d_out;
    dim3 grid(2, 16, 16);  // (w-tiles, h-tiles, n)
    dim3 block(1024);      // 16 waves: one per output channel
    hipLaunchKernelGGL(conv3d_min_softmax, grid, block, 0, stream,
                       x, wgt, bias, out);
}

// Round 8
// 219.594 us; speedup vs baseline: 5.7855x; 2.7553x over previous
//
#include <hip/hip_runtime.h>
#include <math.h>

// Fused Conv3d(3->16, k=3, valid) + bias + min over D + softmax over C.
// N=16, CIN=3, COUT=16, K=3, D=H=W=64 -> out [16,16,62,62] fp32.
//
// R11: R10's wave-per-channel structure (block=1024=16 waves, 2px/thread,
// tile 4h x 32w, grid 512, double-buffered global_load_lds) with the
// weight-residency bug fixed.
// R10 counters (VGPR=24, SGPR=80, VALUBusy 91%, 569us) showed the 81
// weights were resident in NEITHER file: 81+~20 > ~102 SGPR budget, and
// the waves_per_eu(8) 64-VGPR cap excluded them from VGPRs -> compiler
// rematerialized each weight per use (s_load + v_mov per FMA) -> ~3x
// VALU inflation, issue-bound at 8 waves/SIMD.
// Fix: ci loop ROLLED (unroll 1); only 27 weights live at a time ->
// guaranteed SGPR-resident, v_fmac reads the weight as its one legal
// SGPR operand, zero v_mov. Rolled loop's runtime scalar address also
// blocks LICM from hoisting all 81 back. The kd ring is replaced by a
// widened per-chunk accumulator bank Aacc[10][2] (j = dd+2-kd, static
// indices only), carrying 2 slices across chunks. Same FMA count.
// VGPR need ~50 -> 64-bin -> keep 8 waves/SIMD, nothing left to evict.
// Tripwires: VGPR<=64? SGPR~60? WRITE ~4.6MB? dur>=400 => theory wrong.

#define CH 8  // d-slices per staged chunk

__global__ __launch_bounds__(1024)
__attribute__((amdgpu_waves_per_eu(8)))
void conv3d_min_softmax(
    const float* __restrict__ x,     // [16,3,64,64,64]
    const float* __restrict__ wgt,   // [16,3,3,3,3]
    const float* __restrict__ bias,  // [16]
    float* __restrict__ out)         // [16,16,62,62]
{
    const int tid = threadIdx.x;
    // wave id == output channel; readfirstlane forces wave-uniform -> SGPR
    const int wv  = __builtin_amdgcn_readfirstlane(tid >> 6);
    const int l   = tid & 63;
    const int r0  = l >> 4;           // output row within tile (0..3)
    const int cg  = l & 15;           // col-pair group (0..15)
    const int wc  = cg * 2;           // tile col of px0 (even -> 8B aligned)
    const int n   = blockIdx.z;
    const int h0  = blockIdx.y * 4;   // 16 h-tiles cover rows 0..63 (62 valid)
    const int w0  = blockIdx.x * 32;  // 2 w-tiles cover cols 0..63 (62 valid)

    // staged x, double-buffered: [3 ci][CH dd][6 rows][36 cols] = 5184 f
    // = 1296 float4 slots (slot F <-> float index 4F, lane-linear for DMA).
    __shared__ __align__(16) float sx[2][5184];
    // softmax exchange: [128 px][17] (stride 17 -> conflict-free reads)
    __shared__ float sm[128 * 17];

    const float bv = bias[wv];

    // ---- hoisted staging address math (chunk 0) ----
    // slot F -> (ci, dd, r, g):  F = ((ci*8+dd)*6 + r)*9 + g
    int goff[2];  // global BYTE offsets; k=1 used only by tid<272
#pragma unroll
    for (int k = 0; k < 2; ++k) {
        int F = tid + 1024 * k;
        if (F > 1295) F = 1295;          // unused lanes: harmless dup
        int ci  = F / 432;               // 432 = 8*6*9
        int rem = F - ci * 432;
        int dd  = rem / 54;              // 54 = 6*9
        int rr  = rem - dd * 54;
        int rw  = rr / 9;
        int g   = rr - rw * 9;
        int gh  = h0 + rw;  if (gh > 63) gh = 63;   // clamp: halo, unused
        int gw  = w0 + g * 4; if (gw > 60) gw = 60; // clamp: cols>=62 unused
        goff[k] = (((ci * 64 + dd) * 64 + gh) * 64 + gw) * 4;
    }
    const char* xb = (const char*)(x + (size_t)n * 3 * 64 * 64 * 64);

    // accumulator bank for this chunk: Aacc[j][px], j = d' - (c*8 - 2).
    // j=0,1 carry partial sums from the previous chunk; j=0..7 complete
    // this chunk; j=8,9 carry into the next chunk. Static indices only.
    float Aacc[10][2];
#pragma unroll
    for (int j = 0; j < 10; ++j) { Aacc[j][0] = 0.f; Aacc[j][1] = 0.f; }
    float mv[2] = {1e30f, 1e30f};

    // ---- issue chunk 0 DMA (buffer 0) ----
    {
        char* lb = (char*)&sx[0][0];
        __builtin_amdgcn_global_load_lds(
            (const void*)(xb + goff[0]), (void*)(lb + tid * 16), 16, 0, 0);
        if (tid < 272)
            __builtin_amdgcn_global_load_lds(
                (const void*)(xb + goff[1]),
                (void*)(lb + (1024 + tid) * 16), 16, 0, 0);
    }

    for (int c = 0; c < 64 / CH; ++c) {
        // Drains vmcnt(0): chunk c's DMA landed; other buffer now free.
        __syncthreads();

        // ---- issue chunk c+1 DMA; flies during this chunk's compute ----
        if (c < 7) {
            const char* xc = xb + (size_t)(c + 1) * (CH * 64 * 64 * 4);
            char* lb = (char*)&sx[(c + 1) & 1][0];
            __builtin_amdgcn_global_load_lds(
                (const void*)(xc + goff[0]), (void*)(lb + tid * 16),
                16, 0, 0);
            if (tid < 272)
                __builtin_amdgcn_global_load_lds(
                    (const void*)(xc + goff[1]),
                    (void*)(lb + (1024 + tid) * 16), 16, 0, 0);
        }

        const float* S = sx[c & 1];

        // ---- compute: ci ROLLED so only 27 weights live (SGPR-resident)
#pragma unroll 1
        for (int ci = 0; ci < 3; ++ci) {
            float wsc[27];  // wave-uniform -> s_load -> SGPRs
            {
                const float* wp_ = wgt + (wv * 3 + ci) * 27;
#pragma unroll
                for (int i = 0; i < 27; ++i) wsc[i] = wp_[i];
            }
            const float* Sci = S + ci * (CH * 6 * 36) + r0 * 36 + wc;
#pragma unroll
            for (int dd = 0; dd < CH; ++dd) {
#pragma unroll
                for (int kh = 0; kh < 3; ++kh) {
                    const float2 a = *(const float2*)&Sci[(dd * 6 + kh) * 36];
                    const float2 b =
                        *(const float2*)&Sci[(dd * 6 + kh) * 36 + 2];
                    const float row[4] = {a.x, a.y, b.x, b.y};
#pragma unroll
                    for (int kw = 0; kw < 3; ++kw) {
                        const float wk0 = wsc[0  + kh * 3 + kw];  // kd=0
                        const float wk1 = wsc[9  + kh * 3 + kw];  // kd=1
                        const float wk2 = wsc[18 + kh * 3 + kw];  // kd=2
#pragma unroll
                        for (int p = 0; p < 2; ++p) {
                            const float xv = row[kw + p];
                            // x[d] feeds d' = d - kd  ->  j = dd + 2 - kd
                            Aacc[dd + 2][p] = fmaf(xv, wk0, Aacc[dd + 2][p]);
                            Aacc[dd + 1][p] = fmaf(xv, wk1, Aacc[dd + 1][p]);
                            Aacc[dd + 0][p] = fmaf(xv, wk2, Aacc[dd + 0][p]);
                        }
                    }
                }
            }
        }

        // ---- min over completed outputs: j=0..7 <-> d' = c*8-2 .. c*8+5
        const bool full = (c > 0);  // c=0: j=0,1 are d'=-2,-1 (invalid)
#pragma unroll
        for (int j = 0; j < 8; ++j) {
            if (j >= 2 || full) {
                mv[0] = fminf(mv[0], Aacc[j][0]);
                mv[1] = fminf(mv[1], Aacc[j][1]);
            }
        }
        // ---- carry j=8,9 -> j=0,1; zero the rest ----
#pragma unroll
        for (int p = 0; p < 2; ++p) {
            Aacc[0][p] = Aacc[8][p];
            Aacc[1][p] = Aacc[9][p];
        }
#pragma unroll
        for (int j = 2; j < 10; ++j) { Aacc[j][0] = 0.f; Aacc[j][1] = 0.f; }
    }

    // ---- epilogue: exchange via LDS, softmax over 16 channels ----
    const int px0 = r0 * 32 + wc;
    sm[px0 * 17 + wv]       = mv[0] + bv;
    sm[(px0 + 1) * 17 + wv] = mv[1] + bv;
    __syncthreads();

    const int hp = h0 + r0;
#pragma unroll
    for (int pp = 0; pp < 2; ++pp) {
        const int px = px0 + pp;
        float mx = -1e30f;
#pragma unroll
        for (int j = 0; j < 16; ++j) mx = fmaxf(mx, sm[px * 17 + j]);
        float sum = 0.f;
#pragma unroll
        for (int j = 0; j < 16; ++j) sum += __expf(sm[px * 17 + j] - mx);
        const int wp = w0 + wc + pp;
        if (hp < 62 && wp < 62) {
            const float e = __expf(sm[px * 17 + wv] - mx);
            out[(((size_t)n * 16 + wv) * 62 + hp) * 62 + wp] = e / sum;
        }
    }
}

extern "C" void kernel_launch(void* const* d_in, const int* in_sizes, int n_in,
                              void* d_out, int out_size, void* d_ws, size_t ws_size,
                              hipStream_t stream) {
    const float* x    = (const float*)d_in[0];
    const float* wgt  = (const float*)d_in[1];
    const float* bias = (const float*)d_in[2];
    float* out        = (float*)d_out;
    dim3 grid(2, 16, 16);  // (w-tiles, h-tiles, n)
    dim3 block(1024);      // 16 waves: one per output channel
    hipLaunchKernelGGL(conv3d_min_softmax, grid, block, 0, stream,
                       x, wgt, bias, out);
}